// Round 7
// baseline (206.948 us; speedup 1.0000x reference)
//
#include <hip/hip_runtime.h>
#include <hip/hip_cooperative_groups.h>
#include <cfloat>
#include <cmath>

namespace cg = cooperative_groups;

// Problem constants (match reference)
#define IC 480        // IN_CHANNELS
#define OC 18         // OUT_CHANNELS
#define HH 256
#define WW 256
#define HW_ 65536     // H*W
#define NPROP 30      // MAX_PROPOSALS
#define NCG 8         // channel groups for the dot phase
#define CPG 60        // channels per group (480/8)
#define CAP 6144      // candidate capacity (expected survivors ~2600)

// Output layout (14520 floats):
//   [0,60)        instance_coord (30,2) (y,x)
//   [60,90)       scores (30,)
//   [90,14490)    instance_param (480,30)  channels-major (features[0,:,y,x].T)
//   [14490,14520) valid (30,)

// ---------------------------------------------------------------------------
// Bitonic helpers (u64 key = (value_bits<<32) | ~pixel: ascending u64 order ==
// value asc + index desc, so top-of-list = value desc with lower-index ties —
// exact lax.top_k semantics, invariant to atomic append order).
// ---------------------------------------------------------------------------
__device__ __forceinline__ unsigned long long bsort64(unsigned long long key,
                                                      int lane) {
    #pragma unroll
    for (int k = 2; k <= 64; k <<= 1) {
        #pragma unroll
        for (int j = k >> 1; j > 0; j >>= 1) {
            unsigned long long o = __shfl_xor(key, j);
            bool lower = (lane & j) == 0;
            bool asc   = (lane & k) == 0;
            unsigned long long mn = key < o ? key : o;
            unsigned long long mx = key < o ? o : key;
            key = (lower == asc) ? mn : mx;
        }
    }
    return key;   // ascending across lanes
}

__device__ __forceinline__ unsigned long long bmerge64(unsigned long long key,
                                                       int lane) {
    #pragma unroll
    for (int j = 32; j > 0; j >>= 1) {
        unsigned long long o = __shfl_xor(key, j);
        bool lower = (lane & j) == 0;
        unsigned long long mn = key < o ? key : o;
        unsigned long long mx = key < o ? o : key;
        key = lower ? mn : mx;
    }
    return key;   // sorts a bitonic sequence ascending
}

// ---------------------------------------------------------------------------
// Single cooperative kernel, 512 blocks x 256 threads (2 blocks/CU resident):
//  phase 1 (all 512): partial dots, float4 loads — chains bit-identical to the
//    proven 4-kernel version -> same selection.
//  phase 2 (blocks 0..255): sigmoid/clip + avg3 + max5 NMS -> candidate list.
//  phase 3 (block 0, 4 waves): bitonic top-30 + coords/scores/valid writes.
//  phase 4 (blocks 0..56): (480,30) channels-major param gather.
// grid.sync() between phases replaces 3 kernel-launch gaps.
// ---------------------------------------------------------------------------
__global__ __launch_bounds__(256) void k_fused(const float* __restrict__ f,
                                               const float* __restrict__ w,
                                               const float* __restrict__ conv_b,
                                               float* __restrict__ out,
                                               float* __restrict__ partial,
                                               float* __restrict__ cand_val,
                                               int* __restrict__ cand_idx,
                                               int* __restrict__ counter,
                                               int* __restrict__ selpix) {
    cg::grid_group grid = cg::this_grid();
    const int tid = threadIdx.x;
    const int bid = blockIdx.x;

    __shared__ float sw[CPG];
    __shared__ float sc[14][38];            // pool center tile, halo 3
    __shared__ float s2[12][36];            // pool c2 tile, halo 2
    __shared__ unsigned long long lk[256];  // select per-wave sorted lists

    // ---- phase 1: partial dot products ----
    {
        const int cgi = bid >> 6;           // channel group 0..7
        const int bx  = bid & 63;           // pixel-block 0..63
        const int c0  = cgi * CPG;
        if (tid < CPG) sw[tid] = w[17 * IC + c0 + tid];
        if (bid == 0 && tid == 0) atomicExch(counter, 0);
        __syncthreads();
        const int p4 = bx * 256 + tid;      // float4 index [0,16384)
        const float4* __restrict__ f4 = (const float4*)f;
        float ax = 0.f, ay = 0.f, az = 0.f, aww = 0.f;
        #pragma unroll 10
        for (int c = 0; c < CPG; ++c) {
            float4 v = f4[(size_t)(c0 + c) * (HW_ / 4) + p4];
            float wc = sw[c];
            ax  = fmaf(v.x, wc, ax);
            ay  = fmaf(v.y, wc, ay);
            az  = fmaf(v.z, wc, az);
            aww = fmaf(v.w, wc, aww);
        }
        float4 r; r.x = ax; r.y = ay; r.z = az; r.w = aww;
        ((float4*)partial)[(size_t)cgi * (HW_ / 4) + p4] = r;
    }
    grid.sync();

    // ---- phase 2: sigmoid/clip + avg3 + max5 NMS (blocks 0..255) ----
    if (bid < 256) {
        const int ox = (bid & 7) * 32, oy = (bid >> 3) * 8;
        const float b = conv_b[OC - 1];
        for (int i = tid; i < 14 * 38; i += 256) {
            int ly = i / 38, lx = i % 38;
            int gy = oy - 3 + ly, gx = ox - 3 + lx;
            float v = 0.f;                                   // zero pad (avg-sum)
            if (gy >= 0 && gy < HH && gx >= 0 && gx < WW) {
                int p = gy * WW + gx;
                float raw = b;
                #pragma unroll
                for (int g = 0; g < NCG; ++g) raw += partial[g * HW_ + p];
                float s = 1.f / (1.f + expf(-raw));
                v = fminf(fmaxf(s, 1e-4f), 1.f - 1e-4f);
            }
            sc[ly][lx] = v;
        }
        __syncthreads();
        for (int i = tid; i < 12 * 36; i += 256) {
            int ly = i / 36, lx = i % 36;
            int gy = oy - 2 + ly, gx = ox - 2 + lx;
            float v = -FLT_MAX;                              // -inf pad (max)
            if (gy >= 0 && gy < HH && gx >= 0 && gx < WW) {
                float sum = 0.f;
                #pragma unroll
                for (int dy = 0; dy < 3; ++dy)
                    #pragma unroll
                    for (int dx = 0; dx < 3; ++dx)
                        sum += sc[ly + dy][lx + dx];
                v = (sc[ly + 1][lx + 1] + sum / 9.0f) * 0.5f;
            }
            s2[ly][lx] = v;
        }
        __syncthreads();
        const int tx = tid & 31, ty = tid >> 5;
        float c = s2[ty + 2][tx + 2];
        float m = -FLT_MAX;
        #pragma unroll
        for (int dy = 0; dy < 5; ++dy)
            #pragma unroll
            for (int dx = 0; dx < 5; ++dx)
                m = fmaxf(m, s2[ty + dy][tx + dx]);
        if (m == c) {                                        // survivor (c > 0)
            int slot = atomicAdd(counter, 1);
            if (slot < CAP) {
                cand_val[slot] = c;
                cand_idx[slot] = (oy + ty) * WW + (ox + tx);
            }
        }
    }
    grid.sync();

    // ---- phase 3: bitonic top-30 (block 0, 4 waves) ----
    if (bid == 0) {
        const int lane = tid & 63, wv = tid >> 6;
        int n = atomicAdd(counter, 0);
        if (n > CAP) n = CAP;
        unsigned long long R = 0;   // all-zero list is sorted ascending
        for (int base = wv * 64; base < n; base += 256) {
            int j = base + lane;
            unsigned long long key = 0;
            if (j < n) {
                unsigned fb = __float_as_uint(cand_val[j]);   // value>0 -> fb>0
                key = ((unsigned long long)fb << 32)
                    | (unsigned long long)(0xFFFFFFFFu - (unsigned)cand_idx[j]);
            }
            key = bsort64(key, lane);                 // chunk ascending
            unsigned long long crev = __shfl_xor(key, 63);
            R = R > crev ? R : crev;                  // top-64 of union (bitonic)
            R = bmerge64(R, lane);                    // re-sort ascending
        }
        lk[tid] = R;
        __syncthreads();
        if (wv == 0) {
            R = lk[lane];
            #pragma unroll
            for (int ww = 1; ww < 4; ++ww) {
                unsigned long long c2 = lk[ww * 64 + lane];
                unsigned long long crev = __shfl_xor(c2, 63);
                R = R > crev ? R : crev;
                R = bmerge64(R, lane);
            }
            int r = 63 - lane;                        // rank r lives at lane 63-r
            if (r < NPROP) {
                float s = 0.f; int p = 0;
                if (R != 0) {
                    s = __uint_as_float((unsigned)(R >> 32));
                    p = (int)(0xFFFFFFFFu - (unsigned)(R & 0xFFFFFFFFu));
                }
                out[2 * r]     = (float)(p >> 8);     // y
                out[2 * r + 1] = (float)(p & 255);    // x
                out[60 + r] = s;                      // score
                out[60 + NPROP + NPROP * IC + r] = (s > 0.01f) ? 1.f : 0.f;
                selpix[r] = p;
            }
        }
    }
    grid.sync();

    // ---- phase 4: param gather, (480,30) channels-major (blocks 0..56) ----
    {
        int idx = bid * 256 + tid;                    // 0 .. 14399
        if (idx < IC * NPROP) {
            int c = idx / NPROP, i = idx % NPROP;
            out[60 + NPROP + idx] = f[(size_t)c * HW_ + selpix[i]];
        }
    }
}

extern "C" void kernel_launch(void* const* d_in, const int* in_sizes, int n_in,
                              void* d_out, int out_size, void* d_ws, size_t ws_size,
                              hipStream_t stream) {
    const float* features = (const float*)d_in[0];
    const float* conv_w   = (const float*)d_in[1];
    const float* conv_b   = (const float*)d_in[2];
    float* out = (float*)d_out;
    char* ws = (char*)d_ws;

    // ws layout (~2.05 MB total)
    float* partial  = (float*)ws;                               // 8*65536*4 = 2 MB
    float* cand_val = (float*)(ws + (2 << 20));                 // 24 KB
    int*   cand_idx = (int*)  (ws + (2 << 20) + CAP * 4);       // 24 KB
    int*   counter  = (int*)  (ws + (2 << 20) + CAP * 8);       // 4 B
    int*   selpix   = (int*)  (ws + (2 << 20) + CAP * 8 + 16);  // 120 B

    void* args[9] = {
        (void*)&features, (void*)&conv_w, (void*)&conv_b, (void*)&out,
        (void*)&partial, (void*)&cand_val, (void*)&cand_idx,
        (void*)&counter, (void*)&selpix
    };
    hipLaunchCooperativeKernel((const void*)k_fused, dim3(512), dim3(256),
                               args, 0, stream);
}

// Round 8
// 63.843 us; speedup vs baseline: 3.2415x; 3.2415x over previous
//
#include <hip/hip_runtime.h>
#include <cfloat>
#include <cmath>

// Problem constants (match reference)
#define IC 480        // IN_CHANNELS
#define OC 18         // OUT_CHANNELS
#define HH 256
#define WW 256
#define HW_ 65536     // H*W
#define NPROP 30      // MAX_PROPOSALS
#define NCG 8         // channel groups for the dot kernel
#define CPG 60        // channels per group (480/8)
#define CAP 6144      // candidate capacity (expected survivors ~2600)

// Output layout (14520 floats):
//   [0,60)        instance_coord (30,2) (y,x)
//   [60,90)       scores (30,)
//   [90,14490)    instance_param (480,30)  channels-major (features[0,:,y,x].T)
//   [14490,14520) valid (30,)

// ---------------------------------------------------------------------------
// K1: partial dot products  partial[cg][p] = sum_{c in group} f[c,p]*w17[c]
// float4 loads; grid (64, 8) x 256 = 512 blocks. Accumulation chains identical
// to the proven rounds 4-6 -> bit-identical partials -> same selection.
// Block (0,0) zeroes both the candidate counter and the done counter.
// ---------------------------------------------------------------------------
__global__ __launch_bounds__(256) void k_dot(const float* __restrict__ f,
                                             const float* __restrict__ w,
                                             float* __restrict__ partial,
                                             int* __restrict__ counter,
                                             int* __restrict__ done) {
    __shared__ float sw[CPG];
    const int tid = threadIdx.x;
    const int cg = blockIdx.y;
    const int c0 = cg * CPG;
    if (tid < CPG) sw[tid] = w[17 * IC + c0 + tid];
    if (blockIdx.x == 0 && cg == 0 && tid == 0) { *counter = 0; *done = 0; }
    __syncthreads();
    const int p4 = blockIdx.x * 256 + tid;            // float4 index [0,16384)
    const float4* __restrict__ f4 = (const float4*)f;
    float ax = 0.f, ay = 0.f, az = 0.f, aw = 0.f;
    #pragma unroll 10
    for (int c = 0; c < CPG; ++c) {
        float4 v = f4[(size_t)(c0 + c) * (HW_ / 4) + p4];
        float wc = sw[c];
        ax = fmaf(v.x, wc, ax);
        ay = fmaf(v.y, wc, ay);
        az = fmaf(v.z, wc, az);
        aw = fmaf(v.w, wc, aw);
    }
    float4 r; r.x = ax; r.y = ay; r.z = az; r.w = aw;
    ((float4*)partial)[(size_t)cg * (HW_ / 4) + p4] = r;
}

// ---------------------------------------------------------------------------
// Bitonic helpers (u64 key = (value_bits<<32) | ~pixel: ascending u64 order ==
// value asc + index desc -> reading from the top = value desc, lower-index
// ties — exact lax.top_k semantics, invariant to atomic append order).
// ---------------------------------------------------------------------------
__device__ __forceinline__ unsigned long long bsort64(unsigned long long key,
                                                      int lane) {
    #pragma unroll
    for (int k = 2; k <= 64; k <<= 1) {
        #pragma unroll
        for (int j = k >> 1; j > 0; j >>= 1) {
            unsigned long long o = __shfl_xor(key, j);
            bool lower = (lane & j) == 0;
            bool asc   = (lane & k) == 0;
            unsigned long long mn = key < o ? key : o;
            unsigned long long mx = key < o ? o : key;
            key = (lower == asc) ? mn : mx;
        }
    }
    return key;   // ascending across lanes
}

__device__ __forceinline__ unsigned long long bmerge64(unsigned long long key,
                                                       int lane) {
    #pragma unroll
    for (int j = 32; j > 0; j >>= 1) {
        unsigned long long o = __shfl_xor(key, j);
        bool lower = (lane & j) == 0;
        unsigned long long mn = key < o ? key : o;
        unsigned long long mx = key < o ? o : key;
        key = lower ? mn : mx;
    }
    return key;   // sorts a bitonic sequence ascending
}

// ---------------------------------------------------------------------------
// K2: pool + NMS + (last block) top-30 select.
// 256 blocks pool their 32x8 tile and append survivors with agent-scope
// atomic stores; each block release-increments `done`; the 256th finisher
// acquire-reads the full candidate list and runs the 4-wave bitonic top-30,
// writing coords/scores/valid and selpix. No co-residency assumption: the
// selecting block is by definition the last to finish.
// ---------------------------------------------------------------------------
__global__ __launch_bounds__(256) void k_pool_select(
        const float* __restrict__ partial, const float* __restrict__ conv_b,
        float* __restrict__ cand_val, int* __restrict__ cand_idx,
        int* __restrict__ counter, int* __restrict__ done,
        float* __restrict__ out, int* __restrict__ selpix) {
    __shared__ float sc[14][38];            // center tile, halo 3
    __shared__ float s2[12][36];            // c2 tile, halo 2
    __shared__ unsigned long long lk[256];  // select: per-wave sorted lists
    __shared__ int isLast;
    const int tid = threadIdx.x;
    const int ox = (blockIdx.x & 7) * 32, oy = (blockIdx.x >> 3) * 8;
    const float b = conv_b[OC - 1];

    for (int i = tid; i < 14 * 38; i += 256) {
        int ly = i / 38, lx = i % 38;
        int gy = oy - 3 + ly, gx = ox - 3 + lx;
        float v = 0.f;                                   // zero pad (avg-sum)
        if (gy >= 0 && gy < HH && gx >= 0 && gx < WW) {
            int p = gy * WW + gx;
            float raw = b;
            #pragma unroll
            for (int g = 0; g < NCG; ++g) raw += partial[g * HW_ + p];
            float s = 1.f / (1.f + expf(-raw));
            v = fminf(fmaxf(s, 1e-4f), 1.f - 1e-4f);
        }
        sc[ly][lx] = v;
    }
    __syncthreads();

    for (int i = tid; i < 12 * 36; i += 256) {
        int ly = i / 36, lx = i % 36;
        int gy = oy - 2 + ly, gx = ox - 2 + lx;
        float v = -FLT_MAX;                              // -inf pad (max)
        if (gy >= 0 && gy < HH && gx >= 0 && gx < WW) {
            float sum = 0.f;
            #pragma unroll
            for (int dy = 0; dy < 3; ++dy)
                #pragma unroll
                for (int dx = 0; dx < 3; ++dx)
                    sum += sc[ly + dy][lx + dx];
            v = (sc[ly + 1][lx + 1] + sum / 9.0f) * 0.5f;
        }
        s2[ly][lx] = v;
    }
    __syncthreads();

    {
        const int tx = tid & 31, ty = tid >> 5;
        float c = s2[ty + 2][tx + 2];
        float m = -FLT_MAX;
        #pragma unroll
        for (int dy = 0; dy < 5; ++dy)
            #pragma unroll
            for (int dx = 0; dx < 5; ++dx)
                m = fmaxf(m, s2[ty + dy][tx + dx]);
        if (m == c) {                                    // survivor (c > 0)
            int slot = atomicAdd(counter, 1);            // device-scope
            if (slot < CAP) {
                __hip_atomic_store(&cand_val[slot], c, __ATOMIC_RELAXED,
                                   __HIP_MEMORY_SCOPE_AGENT);
                __hip_atomic_store(&cand_idx[slot],
                                   (oy + ty) * WW + (ox + tx),
                                   __ATOMIC_RELAXED, __HIP_MEMORY_SCOPE_AGENT);
            }
        }
    }
    __syncthreads();
    if (tid == 0) {
        int prev = __hip_atomic_fetch_add(done, 1, __ATOMIC_ACQ_REL,
                                          __HIP_MEMORY_SCOPE_AGENT);
        isLast = (prev == 255);
    }
    __syncthreads();
    if (!isLast) return;

    // ---- last block: bitonic top-30 (4 waves) ----
    const int lane = tid & 63, wv = tid >> 6;
    int n = __hip_atomic_load(counter, __ATOMIC_RELAXED,
                              __HIP_MEMORY_SCOPE_AGENT);
    if (n > CAP) n = CAP;
    unsigned long long R = 0;       // all-zero list is sorted ascending
    for (int base = wv * 64; base < n; base += 256) {
        int j = base + lane;
        unsigned long long key = 0;
        if (j < n) {
            float cv = __hip_atomic_load(&cand_val[j], __ATOMIC_RELAXED,
                                         __HIP_MEMORY_SCOPE_AGENT);
            int   ci = __hip_atomic_load(&cand_idx[j], __ATOMIC_RELAXED,
                                         __HIP_MEMORY_SCOPE_AGENT);
            unsigned fb = __float_as_uint(cv);            // value>0 -> fb>0
            key = ((unsigned long long)fb << 32)
                | (unsigned long long)(0xFFFFFFFFu - (unsigned)ci);
        }
        key = bsort64(key, lane);                 // chunk ascending
        unsigned long long crev = __shfl_xor(key, 63);
        R = R > crev ? R : crev;                  // top-64 of union (bitonic)
        R = bmerge64(R, lane);                    // re-sort ascending
    }
    lk[tid] = R;
    __syncthreads();
    if (wv == 0) {
        R = lk[lane];
        #pragma unroll
        for (int ww = 1; ww < 4; ++ww) {
            unsigned long long c2 = lk[ww * 64 + lane];
            unsigned long long crev = __shfl_xor(c2, 63);
            R = R > crev ? R : crev;
            R = bmerge64(R, lane);
        }
        int r = 63 - lane;                        // rank r lives at lane 63-r
        if (r < NPROP) {
            float s = 0.f; int p = 0;
            if (R != 0) {
                s = __uint_as_float((unsigned)(R >> 32));
                p = (int)(0xFFFFFFFFu - (unsigned)(R & 0xFFFFFFFFu));
            }
            out[2 * r]     = (float)(p >> 8);     // y
            out[2 * r + 1] = (float)(p & 255);    // x
            out[60 + r] = s;                      // score
            out[60 + NPROP + NPROP * IC + r] = (s > 0.01f) ? 1.f : 0.f;
            selpix[r] = p;
        }
    }
}

// ---------------------------------------------------------------------------
// K3: gather instance_param in (480, 30) layout: out[90 + c*30 + i] = f[c, p_i]
// ---------------------------------------------------------------------------
__global__ __launch_bounds__(256) void k_gather(const float* __restrict__ f,
                                                const int* __restrict__ selpix,
                                                float* __restrict__ out) {
    __shared__ int sp[NPROP];
    const int tid = threadIdx.x;
    if (tid < NPROP) sp[tid] = selpix[tid];
    __syncthreads();
    int idx = blockIdx.x * 256 + tid;                 // 0 .. 14399
    if (idx < IC * NPROP) {
        int c = idx / NPROP, i = idx % NPROP;
        out[60 + NPROP + idx] = f[(size_t)c * HW_ + sp[i]];
    }
}

extern "C" void kernel_launch(void* const* d_in, const int* in_sizes, int n_in,
                              void* d_out, int out_size, void* d_ws, size_t ws_size,
                              hipStream_t stream) {
    const float* features = (const float*)d_in[0];
    const float* conv_w   = (const float*)d_in[1];
    const float* conv_b   = (const float*)d_in[2];
    float* out = (float*)d_out;
    char* ws = (char*)d_ws;

    // ws layout (~2.05 MB total)
    float* partial  = (float*)ws;                               // 8*65536*4 = 2 MB
    float* cand_val = (float*)(ws + (2 << 20));                 // 24 KB
    int*   cand_idx = (int*)  (ws + (2 << 20) + CAP * 4);       // 24 KB
    int*   counter  = (int*)  (ws + (2 << 20) + CAP * 8);       // 4 B
    int*   done     = (int*)  (ws + (2 << 20) + CAP * 8 + 8);   // 4 B
    int*   selpix   = (int*)  (ws + (2 << 20) + CAP * 8 + 16);  // 120 B

    k_dot        <<<dim3(HW_ / 1024, NCG), 256, 0, stream>>>(features, conv_w,
                                                             partial, counter, done);
    k_pool_select<<<256, 256, 0, stream>>>(partial, conv_b, cand_val, cand_idx,
                                           counter, done, out, selpix);
    k_gather     <<<(IC * NPROP + 255) / 256, 256, 0, stream>>>(features, selpix, out);
}